// Round 2
// baseline (259.488 us; speedup 1.0000x reference)
//
#include <hip/hip_runtime.h>
#include <hip/hip_fp16.h>

#define N_NODES 100000
#define N_EDGES 3200000
#define E_TOT   (N_EDGES + N_NODES)   // 3.3M edges incl self-loops
#define IN_C 128
#define HID  16
#define OUTC 5
#define NEG_SLOPE 0.2f

#define NBKT 391        // buckets of 256 dsts: b = dst >> 8
#define CAP  9216       // per-bucket capacity (mean 8440, +8.5 sigma)
#define HALF_CAP 4608   // per-half-bucket csr region
#define P_TILE 8192
#define PART_GRID ((E_TOT + P_TILE - 1) / P_TILE)   // 403
#define NT 64                                        // nodes per projection tile
#define PROJ_GRID ((N_NODES + NT - 1) / NT)          // 1563
#define AGG_GRID ((N_NODES + 15) / 16)               // 6250 (gat1/gat2 grids)
#define XPAD 132        // padded row stride (floats): 2*132 mod 32 banks = 8 -> 2-way (free)

__device__ __forceinline__ float pk_half2(float a, float b) {
    __half2 h = __halves2half2(__float2half(a), __float2half(b));
    return *(float*)&h;
}
__device__ __forceinline__ float2 unpk_half2(float v) {
    return __half22float2(*(__half2*)&v);
}

// ============ fused: edge partition (blocks 0..402) + layer-1 projection ============
__global__ __launch_bounds__(256) void partproj_k(
    const int* __restrict__ ei, int* __restrict__ gcnt, unsigned* __restrict__ pairs,
    const float* __restrict__ x, const float* __restrict__ W1,
    const float* __restrict__ att_s, const float* __restrict__ att_d,
    __half* __restrict__ h1f, float* __restrict__ a_src, float* __restrict__ a_dst) {
    __shared__ __align__(16) char smem[42240];
    int t = threadIdx.x;
    if (blockIdx.x < PART_GRID) {
        // ---- partition path: no LDS staging; re-read ei (L2-hot) in scatter phase ----
        int* hist = (int*)smem;            // 1564 B
        int* cur  = (int*)(smem + 1564);   // 1564 B
        for (int i = t; i < NBKT; i += 256) hist[i] = 0;
        __syncthreads();
        int base = blockIdx.x * P_TILE;
        int lim = E_TOT - base; if (lim > P_TILE) lim = P_TILE;
        for (int i = t; i < lim; i += 256) {
            int e = base + i;
            int d = (e < N_EDGES) ? ei[N_EDGES + e] : (e - N_EDGES);
            atomicAdd(&hist[d >> 8], 1);
        }
        __syncthreads();
        for (int i = t; i < NBKT; i += 256) {
            int h = hist[i];
            cur[i] = h ? atomicAdd(&gcnt[i], h) : 0;   // reserve [cur, cur+h)
        }
        __syncthreads();
        for (int i = t; i < lim; i += 256) {
            int e = base + i;
            int s, d;
            if (e < N_EDGES) { s = ei[e]; d = ei[N_EDGES + e]; }
            else             { s = e - N_EDGES; d = s; }
            int b = d >> 8;
            int p = atomicAdd(&cur[b], 1);
            if (p >= 0 && p < CAP)
                pairs[(size_t)b * CAP + p] = ((unsigned)s << 8) | (unsigned)(d & 255);
        }
    } else {
        // ---------- projection path: h1 = x@W1, register-tiled 2x2, LDS-pipe optimized ----------
        // sX: 64 rows x 132 floats (padded)  = 33792 B
        // sWt: W transposed, 16 x 132 floats =  8448 B   (total 42240)
        float* sX  = (float*)smem;
        float* sWt = (float*)(smem + 33792);
        int bid = blockIdx.x - PART_GRID;
        int node0 = bid * NT;
        // stage W transposed: sWt[c*XPAD + k] = W1[k*16 + c]
        for (int i = t; i < IN_C * HID; i += 256) {
            int k = i >> 4, c = i & 15;
            sWt[c * XPAD + k] = W1[i];
        }
        // stage x tile with padded rows
        const float4* x4 = (const float4*)x;
        for (int i = t; i < NT * 32; i += 256) {     // 2048 float4
            int r = i >> 5, c4 = i & 31;
            int node = node0 + r;
            float4 v = make_float4(0.f, 0.f, 0.f, 0.f);
            if (node < N_NODES) v = x4[(size_t)node * 32 + c4];
            *((float4*)&sX[r * XPAD + c4 * 4]) = v;
        }
        __syncthreads();
        int rp = t >> 3, cp = t & 7;                 // 32 row-pairs x 8 col-pairs
        const float4* xr0 = (const float4*)&sX[(2 * rp)     * XPAD];
        const float4* xr1 = (const float4*)&sX[(2 * rp + 1) * XPAD];
        const float4* wc0 = (const float4*)&sWt[(2 * cp)     * XPAD];
        const float4* wc1 = (const float4*)&sWt[(2 * cp + 1) * XPAD];
        float4 a00 = make_float4(0.f, 0.f, 0.f, 0.f);
        float4 a01 = a00, a10 = a00, a11 = a00;
        #pragma unroll 8
        for (int k4 = 0; k4 < 32; ++k4) {
            float4 xv0 = xr0[k4], xv1 = xr1[k4];
            float4 wv0 = wc0[k4], wv1 = wc1[k4];
            a00.x += xv0.x * wv0.x; a00.y += xv0.y * wv0.y;
            a00.z += xv0.z * wv0.z; a00.w += xv0.w * wv0.w;
            a01.x += xv0.x * wv1.x; a01.y += xv0.y * wv1.y;
            a01.z += xv0.z * wv1.z; a01.w += xv0.w * wv1.w;
            a10.x += xv1.x * wv0.x; a10.y += xv1.y * wv0.y;
            a10.z += xv1.z * wv0.z; a10.w += xv1.w * wv0.w;
            a11.x += xv1.x * wv1.x; a11.y += xv1.y * wv1.y;
            a11.z += xv1.z * wv1.z; a11.w += xv1.w * wv1.w;
        }
        float h00 = a00.x + a00.y + a00.z + a00.w;   // node 2rp,   col 2cp
        float h01 = a01.x + a01.y + a01.z + a01.w;   // node 2rp,   col 2cp+1
        float h10 = a10.x + a10.y + a10.z + a10.w;   // node 2rp+1, col 2cp
        float h11 = a11.x + a11.y + a11.z + a11.w;   // node 2rp+1, col 2cp+1
        // attention partials + 8-lane shuffle reduce (lane groups of 8 are xor-closed)
        float as0 = att_s[2 * cp], as1 = att_s[2 * cp + 1];
        float ad0 = att_d[2 * cp], ad1 = att_d[2 * cp + 1];
        float ps0 = h00 * as0 + h01 * as1, pd0 = h00 * ad0 + h01 * ad1;
        float ps1 = h10 * as0 + h11 * as1, pd1 = h10 * ad0 + h11 * ad1;
        #pragma unroll
        for (int off = 1; off < 8; off <<= 1) {
            ps0 += __shfl_xor(ps0, off); pd0 += __shfl_xor(pd0, off);
            ps1 += __shfl_xor(ps1, off); pd1 += __shfl_xor(pd1, off);
        }
        int n0 = node0 + 2 * rp, n1 = n0 + 1;
        __half2* hp = (__half2*)h1f;
        if (n0 < N_NODES) {
            hp[(size_t)n0 * 8 + cp] = __halves2half2(__float2half(h00), __float2half(h01));
            if (cp == 0) { a_src[n0] = ps0; a_dst[n0] = pd0; }
        }
        if (n1 < N_NODES) {
            hp[(size_t)n1 * 8 + cp] = __halves2half2(__float2half(h10), __float2half(h11));
            if (cp == 0) { a_src[n1] = ps1; a_dst[n1] = pd1; }
        }
    }
}

// ======== per-half-bucket CSR build; static base = parent*CAP + half*HALF_CAP ====
__global__ __launch_bounds__(256) void build_k(const unsigned* __restrict__ pairs,
                                               const int* __restrict__ gcnt,
                                               int* __restrict__ csr,
                                               int2* __restrict__ rs_cnt) {
    __shared__ int ccnt[128], sexc[128], cur[128];
    int t = threadIdx.x;
    int parent = blockIdx.x >> 1, half = blockIdx.x & 1;
    if (t < 128) ccnt[t] = 0;
    __syncthreads();
    int tot = gcnt[parent];
    if (tot > CAP) tot = CAP; if (tot < 0) tot = 0;
    size_t pb = (size_t)parent * CAP;
    for (int i = t; i < tot; i += 256) {
        unsigned v = pairs[pb + i];
        int dl = (int)(v & 255u);
        if ((dl >> 7) == half) atomicAdd(&ccnt[dl & 127], 1);
    }
    __syncthreads();
    if (t < 128) sexc[t] = ccnt[t];
    __syncthreads();
    for (int off = 1; off < 128; off <<= 1) {
        int xv = 0;
        if (t < 128 && t >= off) xv = sexc[t - off];
        __syncthreads();
        if (t < 128) sexc[t] += xv;
        __syncthreads();
    }
    int gbase = (int)pb + half * HALF_CAP;
    int regend = gbase + HALF_CAP;
    if (t < 128) {
        int excl = sexc[t] - ccnt[t];
        sexc[t] = excl;
        cur[t] = gbase + excl;
        int node = (parent << 8) + (half << 7) + t;
        if (node < N_NODES) {
            int c = ccnt[t];
            if (excl + c > HALF_CAP) c = (excl < HALF_CAP) ? (HALF_CAP - excl) : 0;
            rs_cnt[node] = make_int2(gbase + excl, c);
        }
    }
    __syncthreads();
    for (int i = t; i < tot; i += 256) {
        unsigned v = pairs[pb + i];
        int dl = (int)(v & 255u);
        if ((dl >> 7) == half) {
            int pos = atomicAdd(&cur[dl & 127], 1);
            if (pos < regend) csr[pos] = (int)(v >> 8);
        }
    }
}

// ===== layer-1 aggregate (16 lanes/node) + relu + proj2 fused =====
// Epilogue rework: halving-butterfly reduce (15 shuffles, lane l ends with channel l)
// + per-lane bias/relu + small LDS bounce for the 16->5 W2 projection.
__global__ __launch_bounds__(256) void gat1_k(
    const int* __restrict__ csr, const int2* __restrict__ rs_cnt,
    const __half* __restrict__ h1f, const float* __restrict__ asrc1,
    const float* __restrict__ adst1, const float* __restrict__ b1,
    const float* __restrict__ W2, const float* __restrict__ as2,
    const float* __restrict__ ad2, float4* __restrict__ h2p,
    float* __restrict__ adst2) {
    __shared__ float sW2t[OUTC][20];   // W2 transposed, rows padded to 20 floats (80 B aligned)
    __shared__ float sG[16][16];       // per-local-node g values
    __shared__ float sH2[16][8];       // per-local-node h2 staging
    __shared__ float sAsd[16];         // [0..4]=as2, [8..12]=ad2
    int t = threadIdx.x;
    if (t < 16) sAsd[t] = 0.0f;
    if (t < HID * OUTC) sW2t[t % OUTC][t / OUTC] = W2[t];
    if (t < OUTC) { sAsd[t] = as2[t]; sAsd[8 + t] = ad2[t]; }
    int lane = t & 15;
    float rB1 = b1[lane];              // one 64B line, broadcast
    __syncthreads();

    int node = (blockIdx.x * 256 + t) >> 4;   // grid exact: 6250*256/16 = 100000
    int2 rc = rs_cnt[node];
    int start = rc.x, len = rc.y;
    float ad  = adst1[node];

    float acc[HID];
    #pragma unroll
    for (int c = 0; c < HID; ++c) acc[c] = 0.0f;
    float accd = 0.0f;
    int it = lane;
    for (; it + 16 < len; it += 32) {
        int s0 = csr[start + it];
        int s1 = csr[start + it + 16];
        float v0 = asrc1[s0] + ad;
        float v1 = asrc1[s1] + ad;
        const float4* hp0 = (const float4*)(h1f + (size_t)s0 * HID);
        const float4* hp1 = (const float4*)(h1f + (size_t)s1 * HID);
        float4 p0 = hp0[0], p1 = hp0[1];
        float4 q0 = hp1[0], q1 = hp1[1];
        v0 = (v0 > 0.0f) ? v0 : NEG_SLOPE * v0;
        v1 = (v1 > 0.0f) ? v1 : NEG_SLOPE * v1;
        float e0 = __expf(v0), e1 = __expf(v1);
        accd += e0 + e1;
        {
            float2 f0 = unpk_half2(p0.x), f1 = unpk_half2(p0.y);
            float2 f2 = unpk_half2(p0.z), f3 = unpk_half2(p0.w);
            float2 f4 = unpk_half2(p1.x), f5 = unpk_half2(p1.y);
            float2 f6 = unpk_half2(p1.z), f7 = unpk_half2(p1.w);
            acc[0]  += e0 * f0.x; acc[1]  += e0 * f0.y;
            acc[2]  += e0 * f1.x; acc[3]  += e0 * f1.y;
            acc[4]  += e0 * f2.x; acc[5]  += e0 * f2.y;
            acc[6]  += e0 * f3.x; acc[7]  += e0 * f3.y;
            acc[8]  += e0 * f4.x; acc[9]  += e0 * f4.y;
            acc[10] += e0 * f5.x; acc[11] += e0 * f5.y;
            acc[12] += e0 * f6.x; acc[13] += e0 * f6.y;
            acc[14] += e0 * f7.x; acc[15] += e0 * f7.y;
        }
        {
            float2 f0 = unpk_half2(q0.x), f1 = unpk_half2(q0.y);
            float2 f2 = unpk_half2(q0.z), f3 = unpk_half2(q0.w);
            float2 f4 = unpk_half2(q1.x), f5 = unpk_half2(q1.y);
            float2 f6 = unpk_half2(q1.z), f7 = unpk_half2(q1.w);
            acc[0]  += e1 * f0.x; acc[1]  += e1 * f0.y;
            acc[2]  += e1 * f1.x; acc[3]  += e1 * f1.y;
            acc[4]  += e1 * f2.x; acc[5]  += e1 * f2.y;
            acc[6]  += e1 * f3.x; acc[7]  += e1 * f3.y;
            acc[8]  += e1 * f4.x; acc[9]  += e1 * f4.y;
            acc[10] += e1 * f5.x; acc[11] += e1 * f5.y;
            acc[12] += e1 * f6.x; acc[13] += e1 * f6.y;
            acc[14] += e1 * f7.x; acc[15] += e1 * f7.y;
        }
    }
    if (it < len) {
        int s = csr[start + it];
        float v = asrc1[s] + ad;
        v = (v > 0.0f) ? v : NEG_SLOPE * v;
        float ex = __expf(v);
        accd += ex;
        const float4* hp = (const float4*)(h1f + (size_t)s * HID);
        float4 r0 = hp[0], r1 = hp[1];
        float2 f0 = unpk_half2(r0.x), f1 = unpk_half2(r0.y);
        float2 f2 = unpk_half2(r0.z), f3 = unpk_half2(r0.w);
        float2 f4 = unpk_half2(r1.x), f5 = unpk_half2(r1.y);
        float2 f6 = unpk_half2(r1.z), f7 = unpk_half2(r1.w);
        acc[0]  += ex * f0.x; acc[1]  += ex * f0.y;
        acc[2]  += ex * f1.x; acc[3]  += ex * f1.y;
        acc[4]  += ex * f2.x; acc[5]  += ex * f2.y;
        acc[6]  += ex * f3.x; acc[7]  += ex * f3.y;
        acc[8]  += ex * f4.x; acc[9]  += ex * f4.y;
        acc[10] += ex * f5.x; acc[11] += ex * f5.y;
        acc[12] += ex * f6.x; acc[13] += ex * f6.y;
        acc[14] += ex * f7.x; acc[15] += ex * f7.y;
    }
    // ---- halving butterfly: 15 shuffles; lane l (of 16) ends with channel l in acc[0] ----
    {
        bool b8 = (lane & 8) != 0;
        #pragma unroll
        for (int c = 0; c < 8; ++c) {
            float send = b8 ? acc[c] : acc[c + 8];
            float r = __shfl_xor(send, 8);
            acc[c] = (b8 ? acc[c + 8] : acc[c]) + r;
        }
        bool b4 = (lane & 4) != 0;
        #pragma unroll
        for (int c = 0; c < 4; ++c) {
            float send = b4 ? acc[c] : acc[c + 4];
            float r = __shfl_xor(send, 4);
            acc[c] = (b4 ? acc[c + 4] : acc[c]) + r;
        }
        bool b2 = (lane & 2) != 0;
        #pragma unroll
        for (int c = 0; c < 2; ++c) {
            float send = b2 ? acc[c] : acc[c + 2];
            float r = __shfl_xor(send, 2);
            acc[c] = (b2 ? acc[c + 2] : acc[c]) + r;
        }
        bool b1b = (lane & 1) != 0;
        {
            float send = b1b ? acc[0] : acc[1];
            float r = __shfl_xor(send, 1);
            acc[0] = (b1b ? acc[1] : acc[0]) + r;
        }
    }
    #pragma unroll
    for (int off = 8; off; off >>= 1) accd += __shfl_xor(accd, off);

    float inv = 1.0f / (accd + 1e-16f);
    float g = fmaxf(acc[0] * inv + rB1, 0.0f);   // lane l holds channel l
    int nl = t >> 4;
    sG[nl][lane] = g;                 // wave-local: written & read by the same wave
    if (lane < OUTC) {
        const float4* gp = (const float4*)sG[nl];
        const float4* wp = (const float4*)sW2t[lane];
        float h2v = 0.0f;
        #pragma unroll
        for (int k4 = 0; k4 < 4; ++k4) {
            float4 gv = gp[k4], wv = wp[k4];
            h2v += gv.x * wv.x + gv.y * wv.y + gv.z * wv.z + gv.w * wv.w;
        }
        sH2[nl][lane] = h2v;
        if (lane == 0) {
            float4 hv = *(const float4*)&sH2[nl][0];
            float h24 = sH2[nl][4];
            float4 as4 = *(const float4*)&sAsd[0]; float as_4 = sAsd[4];
            float4 ad4 = *(const float4*)&sAsd[8]; float ad_4 = sAsd[12];
            float s2 = hv.x * as4.x + hv.y * as4.y + hv.z * as4.z + hv.w * as4.w + h24 * as_4;
            float d2 = hv.x * ad4.x + hv.y * ad4.y + hv.z * ad4.z + hv.w * ad4.w + h24 * ad_4;
            adst2[node] = d2;
            float4 r;
            r.x = s2;
            r.y = pk_half2(hv.x, hv.y);
            r.z = pk_half2(hv.z, hv.w);
            r.w = pk_half2(h24, 0.0f);
            h2p[node] = r;
        }
    }
}

// ===== layer-2 aggregate (16 lanes/node, unroll-2) + bias + log_softmax -> out =====
__global__ __launch_bounds__(256) void gat2_k(
    const int* __restrict__ csr, const int2* __restrict__ rs_cnt,
    const float4* __restrict__ h2p, const float* __restrict__ adst2,
    const float* __restrict__ b2, float* __restrict__ out) {
    __shared__ float sB2[OUTC];
    int t = threadIdx.x;
    if (t < OUTC) sB2[t] = b2[t];
    __syncthreads();

    int node = (blockIdx.x * 256 + t) >> 4;
    int lane = t & 15;
    int2 rc = rs_cnt[node];
    int start = rc.x, len = rc.y;
    float ad  = adst2[node];

    float acc[OUTC];
    #pragma unroll
    for (int c = 0; c < OUTC; ++c) acc[c] = 0.0f;
    float accd = 0.0f;
    int it = lane;
    for (; it + 16 < len; it += 32) {
        int s0 = csr[start + it];
        int s1 = csr[start + it + 16];
        float4 r0 = h2p[s0];
        float4 r1 = h2p[s1];
        float v0 = r0.x + ad;
        float v1 = r1.x + ad;
        v0 = (v0 > 0.0f) ? v0 : NEG_SLOPE * v0;
        v1 = (v1 > 0.0f) ? v1 : NEG_SLOPE * v1;
        float e0 = __expf(v0), e1 = __expf(v1);
        accd += e0 + e1;
        float2 a01 = unpk_half2(r0.y), a23 = unpk_half2(r0.z), a4 = unpk_half2(r0.w);
        float2 b01 = unpk_half2(r1.y), b23 = unpk_half2(r1.z), b4 = unpk_half2(r1.w);
        acc[0] += e0 * a01.x + e1 * b01.x;
        acc[1] += e0 * a01.y + e1 * b01.y;
        acc[2] += e0 * a23.x + e1 * b23.x;
        acc[3] += e0 * a23.y + e1 * b23.y;
        acc[4] += e0 * a4.x  + e1 * b4.x;
    }
    if (it < len) {
        int s = csr[start + it];
        float4 r = h2p[s];
        float v = r.x + ad;
        v = (v > 0.0f) ? v : NEG_SLOPE * v;
        float ex = __expf(v);
        accd += ex;
        float2 f01 = unpk_half2(r.y), f23 = unpk_half2(r.z), f4 = unpk_half2(r.w);
        acc[0] += ex * f01.x; acc[1] += ex * f01.y;
        acc[2] += ex * f23.x; acc[3] += ex * f23.y;
        acc[4] += ex * f4.x;
    }
    #pragma unroll
    for (int off = 8; off; off >>= 1) {
        accd += __shfl_xor(accd, off);
        #pragma unroll
        for (int c = 0; c < OUTC; ++c) acc[c] += __shfl_xor(acc[c], off);
    }
    if (lane == 0) {
        float inv = 1.0f / (accd + 1e-16f);
        float val[OUTC];
        float mx = -3.4e38f;
        #pragma unroll
        for (int c = 0; c < OUTC; ++c) {
            val[c] = acc[c] * inv + sB2[c];
            mx = fmaxf(mx, val[c]);
        }
        float se = 0.0f;
        #pragma unroll
        for (int c = 0; c < OUTC; ++c) se += __expf(val[c] - mx);
        float lse = logf(se) + mx;
        #pragma unroll
        for (int c = 0; c < OUTC; ++c)
            out[(size_t)node * OUTC + c] = val[c] - lse;
    }
}

extern "C" void kernel_launch(void* const* d_in, const int* in_sizes, int n_in,
                              void* d_out, int out_size, void* d_ws, size_t ws_size,
                              hipStream_t stream) {
    const float* x    = (const float*)d_in[0];
    const int*   ei   = (const int*)d_in[1];
    const float* W1   = (const float*)d_in[2];
    const float* as1  = (const float*)d_in[3];
    const float* ad1  = (const float*)d_in[4];
    const float* b1   = (const float*)d_in[5];
    const float* W2   = (const float*)d_in[6];
    const float* as2  = (const float*)d_in[7];
    const float* ad2  = (const float*)d_in[8];
    const float* b2   = (const float*)d_in[9];
    float* out = (float*)d_out;

    // workspace (bytes), ~33.6 MB:
    //  pairs:  NBKT*CAP*4 = 14,413,824      [dead after build_k:
    //            h2p  aliases pairs+0        (N float4, 1.6 MB)
    //            adst2 aliases pairs+1.6MB   (N floats) ]
    //  csr:    NBKT*CAP*4 = 14,413,824      (static padded layout, no scan needed)
    //  h1f:    16N __half =  3,200,000
    //  asrc1:  N floats
    //  adst1:  N floats
    //  rs_cnt: N int2     =    800,000
    //  gcnt:   NBKT ints
    char* wsb = (char*)d_ws;
    unsigned* pairs = (unsigned*)wsb;
    float4* h2p     = (float4*)wsb;                       // alias (post-build)
    float*  adst2   = (float*)(wsb + 1600000);            // alias (post-build)
    int*    csr     = (int*)(wsb + 14413824);
    __half* h1f     = (__half*)(wsb + 28827648);
    float*  asrc1   = (float*)(wsb + 32027648);
    float*  adst1   = (float*)(wsb + 32427648);
    int2*   rs_cnt  = (int2*)(wsb + 32827648);
    int*    gcnt    = (int*)(wsb + 33627648);

    // ---- zero bucket totals ----
    hipMemsetAsync(gcnt, 0, NBKT * sizeof(int), stream);
    // ---- fused: edge partition (403 blocks) + layer-1 projection (1563 64-node tiles) ----
    partproj_k<<<PART_GRID + PROJ_GRID, 256, 0, stream>>>(
        ei, gcnt, pairs, x, W1, as1, ad1, h1f, asrc1, adst1);
    // ---- CSR build (782 half-bucket blocks, static offsets) ----
    build_k<<<NBKT * 2, 256, 0, stream>>>(pairs, gcnt, csr, rs_cnt);
    // ---- layer 1 aggregate + relu + layer-2 projection (fused) ----
    gat1_k<<<AGG_GRID, 256, 0, stream>>>(csr, rs_cnt, h1f, asrc1, adst1, b1,
                                         W2, as2, ad2, h2p, adst2);
    // ---- layer 2 aggregate + log_softmax ----
    gat2_k<<<AGG_GRID, 256, 0, stream>>>(csr, rs_cnt, h2p, adst2, b2, out);
}

// Round 4
// 233.393 us; speedup vs baseline: 1.1118x; 1.1118x over previous
//
#include <hip/hip_runtime.h>
#include <hip/hip_fp16.h>

#define N_NODES 100000
#define N_EDGES 3200000
#define E_TOT   (N_EDGES + N_NODES)   // 3.3M edges incl self-loops
#define IN_C 128
#define HID  16
#define OUTC 5
#define NEG_SLOPE 0.2f

#define NBKT 391        // buckets of 256 dsts: b = dst >> 8
#define CAP  9216       // per-bucket capacity (mean 8440, +8.5 sigma)
#define HALF_CAP 4608   // per-half-bucket csr region
#define P_TILE 8192
#define PART_GRID ((E_TOT + P_TILE - 1) / P_TILE)   // 403
#define NT 64                                        // nodes per projection tile
#define PROJ_GRID ((N_NODES + NT - 1) / NT)          // 1563
#define AGG_GRID ((N_NODES + 15) / 16)               // 6250 (gat1/gat2 grids)
#define XPAD 132        // padded row stride (floats): 2*132 mod 32 banks = 8 -> 2-way (free)

__device__ __forceinline__ float pk_half2(float a, float b) {
    __half2 h = __halves2half2(__float2half(a), __float2half(b));
    return *(float*)&h;
}
__device__ __forceinline__ float2 unpk_half2(float v) {
    return __half22float2(*(__half2*)&v);
}

// ============ fused: edge partition (blocks 0..402) + layer-1 projection ============
__global__ __launch_bounds__(256) void partproj_k(
    const int* __restrict__ ei, int* __restrict__ gcnt, unsigned* __restrict__ pairs,
    const float* __restrict__ x, const float* __restrict__ W1,
    const float* __restrict__ att_d,
    __half* __restrict__ h1f, float* __restrict__ a_dst) {
    __shared__ __align__(16) char smem[52288];
    int t = threadIdx.x;
    if (blockIdx.x < PART_GRID) {
        // ---- partition path: staged vbuf/bbuf form (r1-proven; staging enables L2
        //      write-combining on the scattered pairs stores — removing it doubled WRITE_SIZE) ----
        unsigned* vbuf       = (unsigned*)smem;                  // 32768 B
        unsigned short* bbuf = (unsigned short*)(smem + 32768);  // 16384 B
        int* hist            = (int*)(smem + 49152);             // 1564 B
        int* cur             = (int*)(smem + 50716);             // 1564 B
        for (int i = t; i < NBKT; i += 256) hist[i] = 0;
        __syncthreads();
        int base = blockIdx.x * P_TILE;
        int lim = E_TOT - base; if (lim > P_TILE) lim = P_TILE;
        for (int i = t; i < lim; i += 256) {
            int e = base + i;
            int s, d;
            if (e < N_EDGES) { s = ei[e]; d = ei[N_EDGES + e]; }
            else             { s = e - N_EDGES; d = s; }
            int b = d >> 8;
            vbuf[i] = ((unsigned)s << 8) | (unsigned)(d & 255);
            bbuf[i] = (unsigned short)b;
            atomicAdd(&hist[b], 1);
        }
        __syncthreads();
        for (int i = t; i < NBKT; i += 256) {
            int h = hist[i];
            cur[i] = h ? atomicAdd(&gcnt[i], h) : 0;   // reserve [cur, cur+h)
        }
        __syncthreads();
        for (int i = t; i < lim; i += 256) {
            int b = bbuf[i];
            int p = atomicAdd(&cur[b], 1);
            if (p >= 0 && p < CAP) pairs[(size_t)b * CAP + p] = vbuf[i];
        }
    } else {
        // ---------- projection path: h1 = x@W1, register-tiled 2x2, LDS-pipe optimized ----------
        // sX: 64 rows x 132 floats (padded)  = 33792 B
        // sWt: W transposed, 16 x 132 floats =  8448 B   (total 42240 <= 52288)
        float* sX  = (float*)smem;
        float* sWt = (float*)(smem + 33792);
        int bid = blockIdx.x - PART_GRID;
        int node0 = bid * NT;
        // stage W transposed: sWt[c*XPAD + k] = W1[k*16 + c]
        for (int i = t; i < IN_C * HID; i += 256) {
            int k = i >> 4, c = i & 15;
            sWt[c * XPAD + k] = W1[i];
        }
        // stage x tile with padded rows
        const float4* x4 = (const float4*)x;
        for (int i = t; i < NT * 32; i += 256) {     // 2048 float4
            int r = i >> 5, c4 = i & 31;
            int node = node0 + r;
            float4 v = make_float4(0.f, 0.f, 0.f, 0.f);
            if (node < N_NODES) v = x4[(size_t)node * 32 + c4];
            *((float4*)&sX[r * XPAD + c4 * 4]) = v;
        }
        __syncthreads();
        int rp = t >> 3, cp = t & 7;                 // 32 row-pairs x 8 col-pairs
        const float4* xr0 = (const float4*)&sX[(2 * rp)     * XPAD];
        const float4* xr1 = (const float4*)&sX[(2 * rp + 1) * XPAD];
        const float4* wc0 = (const float4*)&sWt[(2 * cp)     * XPAD];
        const float4* wc1 = (const float4*)&sWt[(2 * cp + 1) * XPAD];
        float4 a00 = make_float4(0.f, 0.f, 0.f, 0.f);
        float4 a01 = a00, a10 = a00, a11 = a00;
        #pragma unroll 8
        for (int k4 = 0; k4 < 32; ++k4) {
            float4 xv0 = xr0[k4], xv1 = xr1[k4];
            float4 wv0 = wc0[k4], wv1 = wc1[k4];
            a00.x += xv0.x * wv0.x; a00.y += xv0.y * wv0.y;
            a00.z += xv0.z * wv0.z; a00.w += xv0.w * wv0.w;
            a01.x += xv0.x * wv1.x; a01.y += xv0.y * wv1.y;
            a01.z += xv0.z * wv1.z; a01.w += xv0.w * wv1.w;
            a10.x += xv1.x * wv0.x; a10.y += xv1.y * wv0.y;
            a10.z += xv1.z * wv0.z; a10.w += xv1.w * wv0.w;
            a11.x += xv1.x * wv1.x; a11.y += xv1.y * wv1.y;
            a11.z += xv1.z * wv1.z; a11.w += xv1.w * wv1.w;
        }
        float h00 = a00.x + a00.y + a00.z + a00.w;   // node 2rp,   col 2cp
        float h01 = a01.x + a01.y + a01.z + a01.w;   // node 2rp,   col 2cp+1
        float h10 = a10.x + a10.y + a10.z + a10.w;   // node 2rp+1, col 2cp
        float h11 = a11.x + a11.y + a11.z + a11.w;   // node 2rp+1, col 2cp+1
        // a_dst partials + 8-lane shuffle reduce (lane groups of 8 are xor-closed)
        float ad0 = att_d[2 * cp], ad1 = att_d[2 * cp + 1];
        float pd0 = h00 * ad0 + h01 * ad1;
        float pd1 = h10 * ad0 + h11 * ad1;
        #pragma unroll
        for (int off = 1; off < 8; off <<= 1) {
            pd0 += __shfl_xor(pd0, off);
            pd1 += __shfl_xor(pd1, off);
        }
        int n0 = node0 + 2 * rp, n1 = n0 + 1;
        __half2* hp = (__half2*)h1f;
        if (n0 < N_NODES) {
            hp[(size_t)n0 * 8 + cp] = __halves2half2(__float2half(h00), __float2half(h01));
            if (cp == 0) a_dst[n0] = pd0;
        }
        if (n1 < N_NODES) {
            hp[(size_t)n1 * 8 + cp] = __halves2half2(__float2half(h10), __float2half(h11));
            if (cp == 0) a_dst[n1] = pd1;
        }
    }
}

// ======== per-half-bucket CSR build; static base = parent*CAP + half*HALF_CAP ====
__global__ __launch_bounds__(256) void build_k(const unsigned* __restrict__ pairs,
                                               const int* __restrict__ gcnt,
                                               int* __restrict__ csr,
                                               int2* __restrict__ rs_cnt) {
    __shared__ int ccnt[128], sexc[128], cur[128];
    int t = threadIdx.x;
    int parent = blockIdx.x >> 1, half = blockIdx.x & 1;
    if (t < 128) ccnt[t] = 0;
    __syncthreads();
    int tot = gcnt[parent];
    if (tot > CAP) tot = CAP; if (tot < 0) tot = 0;
    size_t pb = (size_t)parent * CAP;
    for (int i = t; i < tot; i += 256) {
        unsigned v = pairs[pb + i];
        int dl = (int)(v & 255u);
        if ((dl >> 7) == half) atomicAdd(&ccnt[dl & 127], 1);
    }
    __syncthreads();
    if (t < 128) sexc[t] = ccnt[t];
    __syncthreads();
    for (int off = 1; off < 128; off <<= 1) {
        int xv = 0;
        if (t < 128 && t >= off) xv = sexc[t - off];
        __syncthreads();
        if (t < 128) sexc[t] += xv;
        __syncthreads();
    }
    int gbase = (int)pb + half * HALF_CAP;
    int regend = gbase + HALF_CAP;
    if (t < 128) {
        int excl = sexc[t] - ccnt[t];
        sexc[t] = excl;
        cur[t] = gbase + excl;
        int node = (parent << 8) + (half << 7) + t;
        if (node < N_NODES) {
            int c = ccnt[t];
            if (excl + c > HALF_CAP) c = (excl < HALF_CAP) ? (HALF_CAP - excl) : 0;
            rs_cnt[node] = make_int2(gbase + excl, c);
        }
    }
    __syncthreads();
    for (int i = t; i < tot; i += 256) {
        unsigned v = pairs[pb + i];
        int dl = (int)(v & 255u);
        if ((dl >> 7) == half) {
            int pos = atomicAdd(&cur[dl & 127], 1);
            if (pos < regend) csr[pos] = (int)(v >> 8);
        }
    }
}

// ===== layer-1 aggregate (16 lanes/node) + relu + proj2 fused =====
// asrc is RECOMPUTED per edge from the gathered h row (16 FMAs, att in SGPRs) —
// eliminates the 3.3M-random-lane-request asrc1 gather (gather pipe is the scarce
// resource; VALU was 12% busy).
__global__ __launch_bounds__(256) void gat1_k(
    const int* __restrict__ csr, const int2* __restrict__ rs_cnt,
    const __half* __restrict__ h1f, const float* __restrict__ att_s1,
    const float* __restrict__ adst1, const float* __restrict__ b1,
    const float* __restrict__ W2, const float* __restrict__ as2,
    const float* __restrict__ ad2, float4* __restrict__ h2p,
    float* __restrict__ adst2) {
    __shared__ float sW2t[OUTC][20];   // W2 transposed, rows padded to 20 floats
    __shared__ float sG[16][16];       // per-local-node g values
    __shared__ float sH2[16][8];       // per-local-node h2 staging
    __shared__ float sAsd[16];         // [0..4]=as2, [8..12]=ad2
    int t = threadIdx.x;
    if (t < 16) sAsd[t] = 0.0f;
    if (t < HID * OUTC) sW2t[t % OUTC][t / OUTC] = W2[t];
    if (t < OUTC) { sAsd[t] = as2[t]; sAsd[8 + t] = ad2[t]; }
    int lane = t & 15;
    float rB1 = b1[lane];              // one 64B line, broadcast
    // att_src1 (uniform address -> scalar loads, lives in SGPRs)
    float att[HID];
    #pragma unroll
    for (int k = 0; k < HID; ++k) att[k] = att_s1[k];
    __syncthreads();

    int node = (blockIdx.x * 256 + t) >> 4;   // grid exact: 6250*256/16 = 100000
    int2 rc = rs_cnt[node];
    int start = rc.x, len = rc.y;
    float ad  = adst1[node];

    float acc[HID];
    #pragma unroll
    for (int c = 0; c < HID; ++c) acc[c] = 0.0f;
    float accd = 0.0f;
    int it = lane;
    for (; it + 16 < len; it += 32) {
        int s0 = csr[start + it];
        int s1 = csr[start + it + 16];
        const float4* hp0 = (const float4*)(h1f + (size_t)s0 * HID);
        const float4* hp1 = (const float4*)(h1f + (size_t)s1 * HID);
        float4 p0 = hp0[0], p1 = hp0[1];
        float4 q0 = hp1[0], q1 = hp1[1];
        float2 f0 = unpk_half2(p0.x), f1 = unpk_half2(p0.y);
        float2 f2 = unpk_half2(p0.z), f3 = unpk_half2(p0.w);
        float2 f4 = unpk_half2(p1.x), f5 = unpk_half2(p1.y);
        float2 f6 = unpk_half2(p1.z), f7 = unpk_half2(p1.w);
        float2 g0 = unpk_half2(q0.x), g1 = unpk_half2(q0.y);
        float2 g2 = unpk_half2(q0.z), g3 = unpk_half2(q0.w);
        float2 g4 = unpk_half2(q1.x), g5 = unpk_half2(q1.y);
        float2 g6 = unpk_half2(q1.z), g7 = unpk_half2(q1.w);
        float v0 = f0.x*att[0] + f0.y*att[1] + f1.x*att[2] + f1.y*att[3]
                 + f2.x*att[4] + f2.y*att[5] + f3.x*att[6] + f3.y*att[7]
                 + f4.x*att[8] + f4.y*att[9] + f5.x*att[10] + f5.y*att[11]
                 + f6.x*att[12] + f6.y*att[13] + f7.x*att[14] + f7.y*att[15] + ad;
        float v1 = g0.x*att[0] + g0.y*att[1] + g1.x*att[2] + g1.y*att[3]
                 + g2.x*att[4] + g2.y*att[5] + g3.x*att[6] + g3.y*att[7]
                 + g4.x*att[8] + g4.y*att[9] + g5.x*att[10] + g5.y*att[11]
                 + g6.x*att[12] + g6.y*att[13] + g7.x*att[14] + g7.y*att[15] + ad;
        v0 = (v0 > 0.0f) ? v0 : NEG_SLOPE * v0;
        v1 = (v1 > 0.0f) ? v1 : NEG_SLOPE * v1;
        float e0 = __expf(v0), e1 = __expf(v1);
        accd += e0 + e1;
        acc[0]  += e0 * f0.x + e1 * g0.x; acc[1]  += e0 * f0.y + e1 * g0.y;
        acc[2]  += e0 * f1.x + e1 * g1.x; acc[3]  += e0 * f1.y + e1 * g1.y;
        acc[4]  += e0 * f2.x + e1 * g2.x; acc[5]  += e0 * f2.y + e1 * g2.y;
        acc[6]  += e0 * f3.x + e1 * g3.x; acc[7]  += e0 * f3.y + e1 * g3.y;
        acc[8]  += e0 * f4.x + e1 * g4.x; acc[9]  += e0 * f4.y + e1 * g4.y;
        acc[10] += e0 * f5.x + e1 * g5.x; acc[11] += e0 * f5.y + e1 * g5.y;
        acc[12] += e0 * f6.x + e1 * g6.x; acc[13] += e0 * f6.y + e1 * g6.y;
        acc[14] += e0 * f7.x + e1 * g7.x; acc[15] += e0 * f7.y + e1 * g7.y;
    }
    if (it < len) {
        int s = csr[start + it];
        const float4* hp = (const float4*)(h1f + (size_t)s * HID);
        float4 r0 = hp[0], r1 = hp[1];
        float2 f0 = unpk_half2(r0.x), f1 = unpk_half2(r0.y);
        float2 f2 = unpk_half2(r0.z), f3 = unpk_half2(r0.w);
        float2 f4 = unpk_half2(r1.x), f5 = unpk_half2(r1.y);
        float2 f6 = unpk_half2(r1.z), f7 = unpk_half2(r1.w);
        float v = f0.x*att[0] + f0.y*att[1] + f1.x*att[2] + f1.y*att[3]
                + f2.x*att[4] + f2.y*att[5] + f3.x*att[6] + f3.y*att[7]
                + f4.x*att[8] + f4.y*att[9] + f5.x*att[10] + f5.y*att[11]
                + f6.x*att[12] + f6.y*att[13] + f7.x*att[14] + f7.y*att[15] + ad;
        v = (v > 0.0f) ? v : NEG_SLOPE * v;
        float ex = __expf(v);
        accd += ex;
        acc[0]  += ex * f0.x; acc[1]  += ex * f0.y;
        acc[2]  += ex * f1.x; acc[3]  += ex * f1.y;
        acc[4]  += ex * f2.x; acc[5]  += ex * f2.y;
        acc[6]  += ex * f3.x; acc[7]  += ex * f3.y;
        acc[8]  += ex * f4.x; acc[9]  += ex * f4.y;
        acc[10] += ex * f5.x; acc[11] += ex * f5.y;
        acc[12] += ex * f6.x; acc[13] += ex * f6.y;
        acc[14] += ex * f7.x; acc[15] += ex * f7.y;
    }
    // ---- halving butterfly: 15 shuffles; lane l (of 16) ends with channel l in acc[0] ----
    {
        bool b8 = (lane & 8) != 0;
        #pragma unroll
        for (int c = 0; c < 8; ++c) {
            float send = b8 ? acc[c] : acc[c + 8];
            float r = __shfl_xor(send, 8);
            acc[c] = (b8 ? acc[c + 8] : acc[c]) + r;
        }
        bool b4 = (lane & 4) != 0;
        #pragma unroll
        for (int c = 0; c < 4; ++c) {
            float send = b4 ? acc[c] : acc[c + 4];
            float r = __shfl_xor(send, 4);
            acc[c] = (b4 ? acc[c + 4] : acc[c]) + r;
        }
        bool b2 = (lane & 2) != 0;
        #pragma unroll
        for (int c = 0; c < 2; ++c) {
            float send = b2 ? acc[c] : acc[c + 2];
            float r = __shfl_xor(send, 2);
            acc[c] = (b2 ? acc[c + 2] : acc[c]) + r;
        }
        bool b1b = (lane & 1) != 0;
        {
            float send = b1b ? acc[0] : acc[1];
            float r = __shfl_xor(send, 1);
            acc[0] = (b1b ? acc[1] : acc[0]) + r;
        }
    }
    #pragma unroll
    for (int off = 8; off; off >>= 1) accd += __shfl_xor(accd, off);

    float inv = 1.0f / (accd + 1e-16f);
    float g = fmaxf(acc[0] * inv + rB1, 0.0f);   // lane l holds channel l
    int nl = t >> 4;
    sG[nl][lane] = g;                 // wave-local: written & read by the same wave
    if (lane < OUTC) {
        const float4* gp = (const float4*)sG[nl];
        const float4* wp = (const float4*)sW2t[lane];
        float h2v = 0.0f;
        #pragma unroll
        for (int k4 = 0; k4 < 4; ++k4) {
            float4 gv = gp[k4], wv = wp[k4];
            h2v += gv.x * wv.x + gv.y * wv.y + gv.z * wv.z + gv.w * wv.w;
        }
        sH2[nl][lane] = h2v;
        if (lane == 0) {
            float4 hv = *(const float4*)&sH2[nl][0];
            float h24 = sH2[nl][4];
            float4 as4 = *(const float4*)&sAsd[0]; float as_4 = sAsd[4];
            float4 ad4 = *(const float4*)&sAsd[8]; float ad_4 = sAsd[12];
            float s2 = hv.x * as4.x + hv.y * as4.y + hv.z * as4.z + hv.w * as4.w + h24 * as_4;
            float d2 = hv.x * ad4.x + hv.y * ad4.y + hv.z * ad4.z + hv.w * ad4.w + h24 * ad_4;
            adst2[node] = d2;
            float4 r;
            r.x = s2;
            r.y = pk_half2(hv.x, hv.y);
            r.z = pk_half2(hv.z, hv.w);
            r.w = pk_half2(h24, 0.0f);
            h2p[node] = r;
        }
    }
}

// ===== layer-2 aggregate (16 lanes/node, unroll-2) + bias + log_softmax -> out =====
__global__ __launch_bounds__(256) void gat2_k(
    const int* __restrict__ csr, const int2* __restrict__ rs_cnt,
    const float4* __restrict__ h2p, const float* __restrict__ adst2,
    const float* __restrict__ b2, float* __restrict__ out) {
    __shared__ float sB2[OUTC];
    int t = threadIdx.x;
    if (t < OUTC) sB2[t] = b2[t];
    __syncthreads();

    int node = (blockIdx.x * 256 + t) >> 4;
    int lane = t & 15;
    int2 rc = rs_cnt[node];
    int start = rc.x, len = rc.y;
    float ad  = adst2[node];

    float acc[OUTC];
    #pragma unroll
    for (int c = 0; c < OUTC; ++c) acc[c] = 0.0f;
    float accd = 0.0f;
    int it = lane;
    for (; it + 16 < len; it += 32) {
        int s0 = csr[start + it];
        int s1 = csr[start + it + 16];
        float4 r0 = h2p[s0];
        float4 r1 = h2p[s1];
        float v0 = r0.x + ad;
        float v1 = r1.x + ad;
        v0 = (v0 > 0.0f) ? v0 : NEG_SLOPE * v0;
        v1 = (v1 > 0.0f) ? v1 : NEG_SLOPE * v1;
        float e0 = __expf(v0), e1 = __expf(v1);
        accd += e0 + e1;
        float2 a01 = unpk_half2(r0.y), a23 = unpk_half2(r0.z), a4 = unpk_half2(r0.w);
        float2 b01 = unpk_half2(r1.y), b23 = unpk_half2(r1.z), b4 = unpk_half2(r1.w);
        acc[0] += e0 * a01.x + e1 * b01.x;
        acc[1] += e0 * a01.y + e1 * b01.y;
        acc[2] += e0 * a23.x + e1 * b23.x;
        acc[3] += e0 * a23.y + e1 * b23.y;
        acc[4] += e0 * a4.x  + e1 * b4.x;
    }
    if (it < len) {
        int s = csr[start + it];
        float4 r = h2p[s];
        float v = r.x + ad;
        v = (v > 0.0f) ? v : NEG_SLOPE * v;
        float ex = __expf(v);
        accd += ex;
        float2 f01 = unpk_half2(r.y), f23 = unpk_half2(r.z), f4 = unpk_half2(r.w);
        acc[0] += ex * f01.x; acc[1] += ex * f01.y;
        acc[2] += ex * f23.x; acc[3] += ex * f23.y;
        acc[4] += ex * f4.x;
    }
    #pragma unroll
    for (int off = 8; off; off >>= 1) {
        accd += __shfl_xor(accd, off);
        #pragma unroll
        for (int c = 0; c < OUTC; ++c) acc[c] += __shfl_xor(acc[c], off);
    }
    if (lane == 0) {
        float inv = 1.0f / (accd + 1e-16f);
        float val[OUTC];
        float mx = -3.4e38f;
        #pragma unroll
        for (int c = 0; c < OUTC; ++c) {
            val[c] = acc[c] * inv + sB2[c];
            mx = fmaxf(mx, val[c]);
        }
        float se = 0.0f;
        #pragma unroll
        for (int c = 0; c < OUTC; ++c) se += __expf(val[c] - mx);
        float lse = logf(se) + mx;
        #pragma unroll
        for (int c = 0; c < OUTC; ++c)
            out[(size_t)node * OUTC + c] = val[c] - lse;
    }
}

extern "C" void kernel_launch(void* const* d_in, const int* in_sizes, int n_in,
                              void* d_out, int out_size, void* d_ws, size_t ws_size,
                              hipStream_t stream) {
    const float* x    = (const float*)d_in[0];
    const int*   ei   = (const int*)d_in[1];
    const float* W1   = (const float*)d_in[2];
    const float* as1  = (const float*)d_in[3];
    const float* ad1  = (const float*)d_in[4];
    const float* b1   = (const float*)d_in[5];
    const float* W2   = (const float*)d_in[6];
    const float* as2  = (const float*)d_in[7];
    const float* ad2  = (const float*)d_in[8];
    const float* b2   = (const float*)d_in[9];
    float* out = (float*)d_out;

    // workspace (bytes), ~33.6 MB (layout unchanged; asrc1 slot now unused):
    //  pairs:  NBKT*CAP*4 = 14,413,824      [dead after build_k:
    //            h2p  aliases pairs+0        (N float4, 1.6 MB)
    //            adst2 aliases pairs+1.6MB   (N floats) ]
    //  csr:    NBKT*CAP*4 = 14,413,824
    //  h1f:    16N __half =  3,200,000
    //  (unused 400,000)
    //  adst1:  N floats
    //  rs_cnt: N int2     =    800,000
    //  gcnt:   NBKT ints
    char* wsb = (char*)d_ws;
    unsigned* pairs = (unsigned*)wsb;
    float4* h2p     = (float4*)wsb;                       // alias (post-build)
    float*  adst2   = (float*)(wsb + 1600000);            // alias (post-build)
    int*    csr     = (int*)(wsb + 14413824);
    __half* h1f     = (__half*)(wsb + 28827648);
    float*  adst1   = (float*)(wsb + 32427648);
    int2*   rs_cnt  = (int2*)(wsb + 32827648);
    int*    gcnt    = (int*)(wsb + 33627648);

    // ---- zero bucket totals ----
    hipMemsetAsync(gcnt, 0, NBKT * sizeof(int), stream);
    // ---- fused: edge partition (403 blocks) + layer-1 projection (1563 64-node tiles) ----
    partproj_k<<<PART_GRID + PROJ_GRID, 256, 0, stream>>>(
        ei, gcnt, pairs, x, W1, ad1, h1f, adst1);
    // ---- CSR build (782 half-bucket blocks, static offsets) ----
    build_k<<<NBKT * 2, 256, 0, stream>>>(pairs, gcnt, csr, rs_cnt);
    // ---- layer 1 aggregate + relu + layer-2 projection (fused) ----
    gat1_k<<<AGG_GRID, 256, 0, stream>>>(csr, rs_cnt, h1f, as1, adst1, b1,
                                         W2, as2, ad2, h2p, adst2);
    // ---- layer 2 aggregate + log_softmax ----
    gat2_k<<<AGG_GRID, 256, 0, stream>>>(csr, rs_cnt, h2p, adst2, b2, out);
}

// Round 5
// 222.622 us; speedup vs baseline: 1.1656x; 1.0484x over previous
//
#include <hip/hip_runtime.h>
#include <hip/hip_fp16.h>

#define N_NODES 100000
#define N_EDGES 3200000
#define E_TOT   (N_EDGES + N_NODES)   // 3.3M edges incl self-loops
#define IN_C 128
#define HID  16
#define OUTC 5
#define NEG_SLOPE 0.2f

#define NBKT 391        // buckets of 256 dsts: b = dst >> 8
#define CAP  9216       // per-bucket capacity (mean 8440, +8.5 sigma)
#define P_TILE 8192
#define PART_GRID ((E_TOT + P_TILE - 1) / P_TILE)   // 403
#define NT 64                                        // nodes per projection tile
#define PROJ_GRID ((N_NODES + NT - 1) / NT)          // 1563
#define AGG_GRID ((N_NODES + 15) / 16)               // 6250 (gat1/gat2 grids)
#define XPAD 132        // padded row stride (floats): 2*132 mod 32 banks = 8 -> 2-way (free)

__device__ __forceinline__ float pk_half2(float a, float b) {
    __half2 h = __halves2half2(__float2half(a), __float2half(b));
    return *(float*)&h;
}
__device__ __forceinline__ float2 unpk_half2(float v) {
    return __half22float2(*(__half2*)&v);
}

// ============ fused: edge partition (blocks 0..402) + layer-1 projection ============
__global__ __launch_bounds__(256) void partproj_k(
    const int* __restrict__ ei, int* __restrict__ gcnt, unsigned* __restrict__ pairs,
    const float* __restrict__ x, const float* __restrict__ W1,
    const float* __restrict__ att_d,
    __half* __restrict__ h1f, float* __restrict__ a_dst) {
    __shared__ __align__(16) char smem[52288];
    int t = threadIdx.x;
    if (blockIdx.x < PART_GRID) {
        // ---- partition path: staged vbuf/bbuf form (r1-proven; staging enables L2
        //      write-combining on the scattered pairs stores) ----
        unsigned* vbuf       = (unsigned*)smem;                  // 32768 B
        unsigned short* bbuf = (unsigned short*)(smem + 32768);  // 16384 B
        int* hist            = (int*)(smem + 49152);             // 1564 B
        int* cur             = (int*)(smem + 50716);             // 1564 B
        for (int i = t; i < NBKT; i += 256) hist[i] = 0;
        __syncthreads();
        int base = blockIdx.x * P_TILE;
        int lim = E_TOT - base; if (lim > P_TILE) lim = P_TILE;
        for (int i = t; i < lim; i += 256) {
            int e = base + i;
            int s, d;
            if (e < N_EDGES) { s = ei[e]; d = ei[N_EDGES + e]; }
            else             { s = e - N_EDGES; d = s; }
            int b = d >> 8;
            vbuf[i] = ((unsigned)s << 8) | (unsigned)(d & 255);
            bbuf[i] = (unsigned short)b;
            atomicAdd(&hist[b], 1);
        }
        __syncthreads();
        for (int i = t; i < NBKT; i += 256) {
            int h = hist[i];
            cur[i] = h ? atomicAdd(&gcnt[i], h) : 0;   // reserve [cur, cur+h)
        }
        __syncthreads();
        for (int i = t; i < lim; i += 256) {
            int b = bbuf[i];
            int p = atomicAdd(&cur[b], 1);
            if (p >= 0 && p < CAP) pairs[(size_t)b * CAP + p] = vbuf[i];
        }
    } else {
        // ---------- projection path: h1 = x@W1, register-tiled 2x2, LDS-pipe optimized ----------
        float* sX  = (float*)smem;           // 64 x 132 floats = 33792 B
        float* sWt = (float*)(smem + 33792); // 16 x 132 floats =  8448 B
        int bid = blockIdx.x - PART_GRID;
        int node0 = bid * NT;
        for (int i = t; i < IN_C * HID; i += 256) {
            int k = i >> 4, c = i & 15;
            sWt[c * XPAD + k] = W1[i];
        }
        const float4* x4 = (const float4*)x;
        for (int i = t; i < NT * 32; i += 256) {     // 2048 float4
            int r = i >> 5, c4 = i & 31;
            int node = node0 + r;
            float4 v = make_float4(0.f, 0.f, 0.f, 0.f);
            if (node < N_NODES) v = x4[(size_t)node * 32 + c4];
            *((float4*)&sX[r * XPAD + c4 * 4]) = v;
        }
        __syncthreads();
        int rp = t >> 3, cp = t & 7;                 // 32 row-pairs x 8 col-pairs
        const float4* xr0 = (const float4*)&sX[(2 * rp)     * XPAD];
        const float4* xr1 = (const float4*)&sX[(2 * rp + 1) * XPAD];
        const float4* wc0 = (const float4*)&sWt[(2 * cp)     * XPAD];
        const float4* wc1 = (const float4*)&sWt[(2 * cp + 1) * XPAD];
        float4 a00 = make_float4(0.f, 0.f, 0.f, 0.f);
        float4 a01 = a00, a10 = a00, a11 = a00;
        #pragma unroll 8
        for (int k4 = 0; k4 < 32; ++k4) {
            float4 xv0 = xr0[k4], xv1 = xr1[k4];
            float4 wv0 = wc0[k4], wv1 = wc1[k4];
            a00.x += xv0.x * wv0.x; a00.y += xv0.y * wv0.y;
            a00.z += xv0.z * wv0.z; a00.w += xv0.w * wv0.w;
            a01.x += xv0.x * wv1.x; a01.y += xv0.y * wv1.y;
            a01.z += xv0.z * wv1.z; a01.w += xv0.w * wv1.w;
            a10.x += xv1.x * wv0.x; a10.y += xv1.y * wv0.y;
            a10.z += xv1.z * wv0.z; a10.w += xv1.w * wv0.w;
            a11.x += xv1.x * wv1.x; a11.y += xv1.y * wv1.y;
            a11.z += xv1.z * wv1.z; a11.w += xv1.w * wv1.w;
        }
        float h00 = a00.x + a00.y + a00.z + a00.w;
        float h01 = a01.x + a01.y + a01.z + a01.w;
        float h10 = a10.x + a10.y + a10.z + a10.w;
        float h11 = a11.x + a11.y + a11.z + a11.w;
        float ad0 = att_d[2 * cp], ad1 = att_d[2 * cp + 1];
        float pd0 = h00 * ad0 + h01 * ad1;
        float pd1 = h10 * ad0 + h11 * ad1;
        #pragma unroll
        for (int off = 1; off < 8; off <<= 1) {
            pd0 += __shfl_xor(pd0, off);
            pd1 += __shfl_xor(pd1, off);
        }
        int n0 = node0 + 2 * rp, n1 = n0 + 1;
        __half2* hp = (__half2*)h1f;
        if (n0 < N_NODES) {
            hp[(size_t)n0 * 8 + cp] = __halves2half2(__float2half(h00), __float2half(h01));
            if (cp == 0) a_dst[n0] = pd0;
        }
        if (n1 < N_NODES) {
            hp[(size_t)n1 * 8 + cp] = __halves2half2(__float2half(h10), __float2half(h11));
            if (cp == 0) a_dst[n1] = pd1;
        }
    }
}

// ======== CSR build: ONE 512-thread block per bucket, 256 counters, single pass ====
// (replaces the 2x half-bucket form: pairs read once instead of twice, atomics halved)
__global__ __launch_bounds__(512) void build_k(const unsigned* __restrict__ pairs,
                                               const int* __restrict__ gcnt,
                                               int* __restrict__ csr,
                                               int2* __restrict__ rs_cnt) {
    __shared__ int ccnt[256], sexc[256], cur[256];
    int t = threadIdx.x;
    int parent = blockIdx.x;
    if (t < 256) ccnt[t] = 0;
    __syncthreads();
    int tot = gcnt[parent];
    if (tot > CAP) tot = CAP; if (tot < 0) tot = 0;
    size_t pb = (size_t)parent * CAP;
    for (int i = t; i < tot; i += 512) {
        unsigned v = pairs[pb + i];
        atomicAdd(&ccnt[v & 255u], 1);
    }
    __syncthreads();
    if (t < 256) sexc[t] = ccnt[t];
    __syncthreads();
    for (int off = 1; off < 256; off <<= 1) {
        int xv = 0;
        if (t < 256 && t >= off) xv = sexc[t - off];
        __syncthreads();
        if (t < 256) sexc[t] += xv;
        __syncthreads();
    }
    int gbase = (int)pb;
    int regend = gbase + CAP;
    if (t < 256) {
        int excl = sexc[t] - ccnt[t];
        cur[t] = gbase + excl;
        int node = (parent << 8) + t;
        if (node < N_NODES) {
            int c = ccnt[t];
            if (excl + c > CAP) c = (excl < CAP) ? (CAP - excl) : 0;
            rs_cnt[node] = make_int2(gbase + excl, c);
        }
    }
    __syncthreads();
    for (int i = t; i < tot; i += 512) {
        unsigned v = pairs[pb + i];
        int pos = atomicAdd(&cur[v & 255u], 1);
        if (pos < regend) csr[pos] = (int)(v >> 8);
    }
}

// ===== layer-1 aggregate: pair-split channels (lane pair shares an edge; each lane
// loads ONE float4 = half the h1 row). Halves gather line-touches; acc[8] not acc[16].
__global__ __launch_bounds__(256) void gat1_k(
    const int* __restrict__ csr, const int2* __restrict__ rs_cnt,
    const __half* __restrict__ h1f, const float* __restrict__ att_s1,
    const float* __restrict__ adst1, const float* __restrict__ b1,
    const float* __restrict__ W2, const float* __restrict__ as2,
    const float* __restrict__ ad2, float4* __restrict__ h2p,
    float* __restrict__ adst2) {
    __shared__ float sW2t[OUTC][20];   // W2 transposed, rows padded to 20 floats
    __shared__ float sG[16][16];       // per-local-node g values
    __shared__ float sH2[16][8];       // per-local-node h2 staging
    __shared__ float sAsd[16];         // [0..4]=as2, [8..12]=ad2
    int t = threadIdx.x;
    if (t < 16) sAsd[t] = 0.0f;
    if (t < HID * OUTC) sW2t[t % OUTC][t / OUTC] = W2[t];
    if (t < OUTC) { sAsd[t] = as2[t]; sAsd[8 + t] = ad2[t]; }
    int lane  = t & 15;
    int sub   = lane & 1;        // which half of the channel vector this lane owns
    int eslot = lane >> 1;       // 8 edge slots per node
    // butterfly output channel for this lane: ch = sub*8 + 4*e0 + 2*e1 + e2
    int ch = sub * 8 + ((lane >> 1) & 1) * 4 + ((lane >> 2) & 1) * 2 + ((lane >> 3) & 1);
    float rB1 = b1[ch];
    // this lane's half of att_src1 (8 floats, compile-time indexed -> registers)
    float attr[8];
    #pragma unroll
    for (int j = 0; j < 8; ++j) attr[j] = att_s1[sub * 8 + j];
    __syncthreads();

    int node = (blockIdx.x * 256 + t) >> 4;   // grid exact: 6250*256/16 = 100000
    int2 rc = rs_cnt[node];
    int start = rc.x, len = rc.y;
    float ad  = adst1[node];

    float acc[8];
    #pragma unroll
    for (int c = 0; c < 8; ++c) acc[c] = 0.0f;
    float accd = 0.0f;
    int it = eslot;
    for (; it + 8 < len; it += 16) {
        int s0 = csr[start + it];
        int s1 = csr[start + it + 8];
        // each lane loads its half-row (16B); pair lanes hit consecutive 16B of one line
        float4 p = *(const float4*)(h1f + (size_t)s0 * HID + sub * 8);
        float4 q = *(const float4*)(h1f + (size_t)s1 * HID + sub * 8);
        float2 f0 = unpk_half2(p.x), f1 = unpk_half2(p.y);
        float2 f2 = unpk_half2(p.z), f3 = unpk_half2(p.w);
        float2 g0 = unpk_half2(q.x), g1 = unpk_half2(q.y);
        float2 g2 = unpk_half2(q.z), g3 = unpk_half2(q.w);
        float pp0 = f0.x*attr[0] + f0.y*attr[1] + f1.x*attr[2] + f1.y*attr[3]
                  + f2.x*attr[4] + f2.y*attr[5] + f3.x*attr[6] + f3.y*attr[7];
        float pp1 = g0.x*attr[0] + g0.y*attr[1] + g1.x*attr[2] + g1.y*attr[3]
                  + g2.x*attr[4] + g2.y*attr[5] + g3.x*attr[6] + g3.y*attr[7];
        float v0 = pp0 + __shfl_xor(pp0, 1) + ad;   // pair-sum -> full att_src dot
        float v1 = pp1 + __shfl_xor(pp1, 1) + ad;
        v0 = (v0 > 0.0f) ? v0 : NEG_SLOPE * v0;
        v1 = (v1 > 0.0f) ? v1 : NEG_SLOPE * v1;
        float e0 = __expf(v0), e1 = __expf(v1);
        accd += e0 + e1;
        acc[0] += e0 * f0.x + e1 * g0.x; acc[1] += e0 * f0.y + e1 * g0.y;
        acc[2] += e0 * f1.x + e1 * g1.x; acc[3] += e0 * f1.y + e1 * g1.y;
        acc[4] += e0 * f2.x + e1 * g2.x; acc[5] += e0 * f2.y + e1 * g2.y;
        acc[6] += e0 * f3.x + e1 * g3.x; acc[7] += e0 * f3.y + e1 * g3.y;
    }
    if (it < len) {
        int s = csr[start + it];
        float4 p = *(const float4*)(h1f + (size_t)s * HID + sub * 8);
        float2 f0 = unpk_half2(p.x), f1 = unpk_half2(p.y);
        float2 f2 = unpk_half2(p.z), f3 = unpk_half2(p.w);
        float pp = f0.x*attr[0] + f0.y*attr[1] + f1.x*attr[2] + f1.y*attr[3]
                 + f2.x*attr[4] + f2.y*attr[5] + f3.x*attr[6] + f3.y*attr[7];
        float v = pp + __shfl_xor(pp, 1) + ad;
        v = (v > 0.0f) ? v : NEG_SLOPE * v;
        float ex = __expf(v);
        accd += ex;
        acc[0] += ex * f0.x; acc[1] += ex * f0.y;
        acc[2] += ex * f1.x; acc[3] += ex * f1.y;
        acc[4] += ex * f2.x; acc[5] += ex * f2.y;
        acc[6] += ex * f3.x; acc[7] += ex * f3.y;
    }
    // ---- halving butterfly across the 8 edge-slots (xor 2,4,8): 7 shuffles ----
    {
        bool b2 = (lane & 2) != 0;
        #pragma unroll
        for (int c = 0; c < 4; ++c) {
            float send = b2 ? acc[c] : acc[c + 4];
            float r = __shfl_xor(send, 2);
            acc[c] = (b2 ? acc[c + 4] : acc[c]) + r;
        }
        bool b4 = (lane & 4) != 0;
        #pragma unroll
        for (int c = 0; c < 2; ++c) {
            float send = b4 ? acc[c] : acc[c + 2];
            float r = __shfl_xor(send, 4);
            acc[c] = (b4 ? acc[c + 2] : acc[c]) + r;
        }
        bool b8 = (lane & 8) != 0;
        {
            float send = b8 ? acc[0] : acc[1];
            float r = __shfl_xor(send, 8);
            acc[0] = (b8 ? acc[1] : acc[0]) + r;
        }
    }
    // accd: pair-identical already; sum across edge-slots
    accd += __shfl_xor(accd, 2);
    accd += __shfl_xor(accd, 4);
    accd += __shfl_xor(accd, 8);

    float inv = 1.0f / (accd + 1e-16f);
    float g = fmaxf(acc[0] * inv + rB1, 0.0f);   // lane holds channel ch
    int nl = t >> 4;
    sG[nl][ch] = g;                 // wave-local: written & read by the same wave
    if (lane < OUTC) {
        const float4* gp = (const float4*)sG[nl];
        const float4* wp = (const float4*)sW2t[lane];
        float h2v = 0.0f;
        #pragma unroll
        for (int k4 = 0; k4 < 4; ++k4) {
            float4 gv = gp[k4], wv = wp[k4];
            h2v += gv.x * wv.x + gv.y * wv.y + gv.z * wv.z + gv.w * wv.w;
        }
        sH2[nl][lane] = h2v;
        if (lane == 0) {
            float4 hv = *(const float4*)&sH2[nl][0];
            float h24 = sH2[nl][4];
            float4 as4 = *(const float4*)&sAsd[0]; float as_4 = sAsd[4];
            float4 ad4 = *(const float4*)&sAsd[8]; float ad_4 = sAsd[12];
            float s2 = hv.x * as4.x + hv.y * as4.y + hv.z * as4.z + hv.w * as4.w + h24 * as_4;
            float d2 = hv.x * ad4.x + hv.y * ad4.y + hv.z * ad4.z + hv.w * ad4.w + h24 * ad_4;
            adst2[node] = d2;
            float4 r;
            r.x = s2;
            r.y = pk_half2(hv.x, hv.y);
            r.z = pk_half2(hv.z, hv.w);
            r.w = pk_half2(h24, 0.0f);
            h2p[node] = r;
        }
    }
}

// ===== layer-2 aggregate (16 lanes/node, unroll-2) + bias + log_softmax -> out =====
__global__ __launch_bounds__(256) void gat2_k(
    const int* __restrict__ csr, const int2* __restrict__ rs_cnt,
    const float4* __restrict__ h2p, const float* __restrict__ adst2,
    const float* __restrict__ b2, float* __restrict__ out) {
    __shared__ float sB2[OUTC];
    int t = threadIdx.x;
    if (t < OUTC) sB2[t] = b2[t];
    __syncthreads();

    int node = (blockIdx.x * 256 + t) >> 4;
    int lane = t & 15;
    int2 rc = rs_cnt[node];
    int start = rc.x, len = rc.y;
    float ad  = adst2[node];

    float acc[OUTC];
    #pragma unroll
    for (int c = 0; c < OUTC; ++c) acc[c] = 0.0f;
    float accd = 0.0f;
    int it = lane;
    for (; it + 16 < len; it += 32) {
        int s0 = csr[start + it];
        int s1 = csr[start + it + 16];
        float4 r0 = h2p[s0];
        float4 r1 = h2p[s1];
        float v0 = r0.x + ad;
        float v1 = r1.x + ad;
        v0 = (v0 > 0.0f) ? v0 : NEG_SLOPE * v0;
        v1 = (v1 > 0.0f) ? v1 : NEG_SLOPE * v1;
        float e0 = __expf(v0), e1 = __expf(v1);
        accd += e0 + e1;
        float2 a01 = unpk_half2(r0.y), a23 = unpk_half2(r0.z), a4 = unpk_half2(r0.w);
        float2 b01 = unpk_half2(r1.y), b23 = unpk_half2(r1.z), b4 = unpk_half2(r1.w);
        acc[0] += e0 * a01.x + e1 * b01.x;
        acc[1] += e0 * a01.y + e1 * b01.y;
        acc[2] += e0 * a23.x + e1 * b23.x;
        acc[3] += e0 * a23.y + e1 * b23.y;
        acc[4] += e0 * a4.x  + e1 * b4.x;
    }
    if (it < len) {
        int s = csr[start + it];
        float4 r = h2p[s];
        float v = r.x + ad;
        v = (v > 0.0f) ? v : NEG_SLOPE * v;
        float ex = __expf(v);
        accd += ex;
        float2 f01 = unpk_half2(r.y), f23 = unpk_half2(r.z), f4 = unpk_half2(r.w);
        acc[0] += ex * f01.x; acc[1] += ex * f01.y;
        acc[2] += ex * f23.x; acc[3] += ex * f23.y;
        acc[4] += ex * f4.x;
    }
    #pragma unroll
    for (int off = 8; off; off >>= 1) {
        accd += __shfl_xor(accd, off);
        #pragma unroll
        for (int c = 0; c < OUTC; ++c) acc[c] += __shfl_xor(acc[c], off);
    }
    if (lane == 0) {
        float inv = 1.0f / (accd + 1e-16f);
        float val[OUTC];
        float mx = -3.4e38f;
        #pragma unroll
        for (int c = 0; c < OUTC; ++c) {
            val[c] = acc[c] * inv + sB2[c];
            mx = fmaxf(mx, val[c]);
        }
        float se = 0.0f;
        #pragma unroll
        for (int c = 0; c < OUTC; ++c) se += __expf(val[c] - mx);
        float lse = logf(se) + mx;
        #pragma unroll
        for (int c = 0; c < OUTC; ++c)
            out[(size_t)node * OUTC + c] = val[c] - lse;
    }
}

extern "C" void kernel_launch(void* const* d_in, const int* in_sizes, int n_in,
                              void* d_out, int out_size, void* d_ws, size_t ws_size,
                              hipStream_t stream) {
    const float* x    = (const float*)d_in[0];
    const int*   ei   = (const int*)d_in[1];
    const float* W1   = (const float*)d_in[2];
    const float* as1  = (const float*)d_in[3];
    const float* ad1  = (const float*)d_in[4];
    const float* b1   = (const float*)d_in[5];
    const float* W2   = (const float*)d_in[6];
    const float* as2  = (const float*)d_in[7];
    const float* ad2  = (const float*)d_in[8];
    const float* b2   = (const float*)d_in[9];
    float* out = (float*)d_out;

    char* wsb = (char*)d_ws;
    unsigned* pairs = (unsigned*)wsb;
    float4* h2p     = (float4*)wsb;                       // alias (post-build)
    float*  adst2   = (float*)(wsb + 1600000);            // alias (post-build)
    int*    csr     = (int*)(wsb + 14413824);
    __half* h1f     = (__half*)(wsb + 28827648);
    float*  adst1   = (float*)(wsb + 32427648);
    int2*   rs_cnt  = (int2*)(wsb + 32827648);
    int*    gcnt    = (int*)(wsb + 33627648);

    // ---- zero bucket totals ----
    hipMemsetAsync(gcnt, 0, NBKT * sizeof(int), stream);
    // ---- fused: edge partition (403 blocks) + layer-1 projection (1563 64-node tiles) ----
    partproj_k<<<PART_GRID + PROJ_GRID, 256, 0, stream>>>(
        ei, gcnt, pairs, x, W1, ad1, h1f, adst1);
    // ---- CSR build (391 one-per-bucket 512-thread blocks, single pass) ----
    build_k<<<NBKT, 512, 0, stream>>>(pairs, gcnt, csr, rs_cnt);
    // ---- layer 1 aggregate + relu + layer-2 projection (fused) ----
    gat1_k<<<AGG_GRID, 256, 0, stream>>>(csr, rs_cnt, h1f, as1, adst1, b1,
                                         W2, as2, ad2, h2p, adst2);
    // ---- layer 2 aggregate + log_softmax ----
    gat2_k<<<AGG_GRID, 256, 0, stream>>>(csr, rs_cnt, h2p, adst2, b2, out);
}